// Round 14
// baseline (118.189 us; speedup 1.0000x reference)
//
#include <hip/hip_runtime.h>
#include <math.h>

#define NB   64
#define NC_  256
#define NH   40
#define NW   40
#define NHW  1600
#define NWIN 64
#define CH   4          // channels per sample block

typedef float f32x4 __attribute__((ext_vector_type(4)));

// ---------------------------------------------------------------------------
// FUSED Kernel A+B: pool + BN/ReLU + co + M + folded bilinear coefficients.
// One block per (b, wh): 256 threads = 256 channels.
// Coefficients for the no-LDS gather sampler:
//   cw4[px] = weights*validity*a_k  (a=2 if clamped corner col<30 else 1;
//             invalid corners carry weight 0)
//   cpk[px] = {off00|(off01<<16), off10|(off11<<16)}, off = yc*40+xc with
//             coords clamped to [0,39] (reads are weight-masked).
// The +1e-5 additive term (bounded by 2e-5) is dropped — 4 orders of
// magnitude below the 0.17 validation threshold.
// ---------------------------------------------------------------------------
__global__ __launch_bounds__(256) void pool_co_kernel(
    const float* __restrict__ feats,
    const float* __restrict__ gd, const float* __restrict__ bed,
    const float* __restrict__ rmd, const float* __restrict__ rvd,
    const float* __restrict__ wd, const float* __restrict__ bd,
    float4* __restrict__ cw4, int2* __restrict__ cpk)
{
    __shared__ float pl[8][NC_];      // pooled [ww][c]
    __shared__ __align__(16) float swd[8 * NC_];
    __shared__ float sco[8][8];
    __shared__ float sM6[8][6];

    const int blk = blockIdx.x;       // b*8 + wh
    const int b   = blk >> 3;
    const int wh  = blk & 7;
    const int t   = threadIdx.x;      // channel

    // stage wd (8x256 floats) into LDS, coalesced
    for (int i = t; i < 512; i += 256)
        ((f32x4*)swd)[i] = ((const f32x4*)wd)[i];

    // 1+2) register pooling for channel t over the wh band
    {
        const f32x4* src = (const f32x4*)(feats + ((size_t)(b * NC_ + t)) * NHW
                                          + wh * 5 * NW);
        float acc[8] = {0.f, 0.f, 0.f, 0.f, 0.f, 0.f, 0.f, 0.f};
        #pragma unroll
        for (int r = 0; r < 5; ++r) {
            #pragma unroll
            for (int j = 0; j < 10; ++j) {
                const f32x4 v = src[r * 10 + j];
                #pragma unroll
                for (int k = 0; k < 4; ++k)
                    acc[(4 * j + k) / 5] += v[k];   // static col-group map
            }
        }
        const float inv  = gd[t] / sqrtf(rvd[t] + 1e-5f);
        const float beta = bed[t] - rmd[t] * inv;
        #pragma unroll
        for (int ww = 0; ww < 8; ++ww) {
            const float mean = acc[ww] * (1.0f / 25.0f);
            const float f2m  = (ww < 6) ? (2.0f * mean) : (mean + 1e-5f);
            pl[ww][t] = fmaxf(f2m * inv + beta, 0.0f);
        }
    }
    __syncthreads();

    // 3) co: two windows per wave (32-lane segments)
    {
        const int w = t >> 5;         // window ww
        const int s = t & 31;
        float po[8] = {0.f, 0.f, 0.f, 0.f, 0.f, 0.f, 0.f, 0.f};
        #pragma unroll
        for (int k = 0; k < 8; ++k) {
            const int c2 = s + 32 * k;
            const float p = pl[w][c2];
            #pragma unroll
            for (int o = 0; o < 8; ++o)
                po[o] += p * swd[o * NC_ + c2];
        }
        #pragma unroll
        for (int o = 0; o < 8; ++o) {
            #pragma unroll
            for (int off = 16; off > 0; off >>= 1)
                po[o] += __shfl_down(po[o], off, 32);
        }
        if (s == 0) {
            #pragma unroll
            for (int o = 0; o < 8; ++o) sco[w][o] = po[o] + bd[o];
        }
    }
    __syncthreads();

    // 4) affine M per window
    if (t < 8) {
        const float xr = sco[t][0], yr = sco[t][1], sx = sco[t][2], sy = sco[t][3];
        const float tx0 = sco[t][4], tx1 = sco[t][5], ty0 = sco[t][6], ty1 = sco[t][7];
        const float cx = cosf(xr), sxr = sinf(xr);
        const float cy = cosf(yr), syr = sinf(yr);
        const float s = sx * sy;
        sM6[t][0] = (cx * cy - sxr * syr) * s;           // M00
        sM6[t][1] = (cx * syr + sxr * cy) * s;           // M01
        sM6[t][2] = sx * (cx * ty0 + sxr * ty1) + tx0;   // M02
        sM6[t][3] = (-sxr * cy - cx * syr) * s;          // M10
        sM6[t][4] = (-sxr * syr + cx * cy) * s;          // M11
        sM6[t][5] = sx * (-sxr * ty0 + cx * ty1) + tx1;  // M12
    }
    __syncthreads();

    // 5) folded bilinear coefficients: 8 windows x 25 px
    if (t < 200) {
        const int w   = t / 25;       // ww
        const int pxi = t - w * 25;
        const int ii  = pxi / 5;
        const int jj  = pxi - ii * 5;
        const float* m = sM6[w];

        const float wcx = (float)(jj - 2) * (2.0f / 39.0f);
        const float wcy = (float)(ii - 2) * (2.0f / 39.0f);
        const float gx = m[0] * wcx + m[1] * wcy + m[2];
        const float gy = m[3] * wcx + m[4] * wcy + m[5];

        float x = (gx + 1.0f) * 19.5f;
        float y = (gy + 1.0f) * 19.5f;
        x = fminf(fmaxf(x, -1.0e6f), 1.0e6f);
        y = fminf(fmaxf(y, -1.0e6f), 1.0e6f);

        const float x0f = floorf(x), y0f = floorf(y);
        const int x0 = (int)x0f, y0 = (int)y0f;
        const int x1 = x0 + 1,  y1 = y0 + 1;
        const float fx = x - x0f, fy = y - y0f;

        const bool xv0 = (x0 >= 0) & (x0 <= NW - 1);
        const bool xv1 = (x1 >= 0) & (x1 <= NW - 1);
        const bool yv0 = (y0 >= 0) & (y0 <= NH - 1);
        const bool yv1 = (y1 >= 0) & (y1 <= NH - 1);

        const float w00 = (1.f - fx) * (1.f - fy) * (float)(xv0 && yv0);
        const float w01 = fx * (1.f - fy) * (float)(xv1 && yv0);
        const float w10 = (1.f - fx) * fy * (float)(xv0 && yv1);
        const float w11 = fx * fy * (float)(xv1 && yv1);

        const int xc0 = min(max(x0, 0), NW - 1);
        const int xc1 = min(max(x1, 0), NW - 1);
        const int yc0 = min(max(y0, 0), NH - 1);
        const int yc1 = min(max(y1, 0), NH - 1);
        const float a0 = (xc0 < 30) ? 2.f : 1.f;
        const float a1 = (xc1 < 30) ? 2.f : 1.f;

        float4 wvec;
        wvec.x = w00 * a0;
        wvec.y = w01 * a1;
        wvec.z = w10 * a0;
        wvec.w = w11 * a1;

        int2 pk;
        pk.x = (yc0 * NW + xc0) | ((yc0 * NW + xc1) << 16);
        pk.y = (yc1 * NW + xc0) | ((yc1 * NW + xc1) << 16);

        const int h    = wh * 5 + ii;
        const int wcol = w * 5 + jj;
        const int pidx = b * NHW + h * NW + wcol;
        cw4[pidx] = wvec;
        cpk[pidx] = pk;
    }
}

// ---------------------------------------------------------------------------
// Kernel C: no-LDS direct-gather sampler. One block per (b, cgroup of 4);
// 320 threads. Working set 4 x 6.4KB fits L1; no staging, no barrier, no
// LDS cap -> occupancy bounded only by VGPRs; 80 independent gathers/thread.
// ---------------------------------------------------------------------------
__global__ __launch_bounds__(320) void sample_gather_kernel(
    const float* __restrict__ feats,
    const float4* __restrict__ cw4, const int2* __restrict__ cpk,
    float* __restrict__ out)
{
    const int blk = blockIdx.x;         // b*(256/CH) + cg
    const int b   = blk >> 6;           // 256/CH = 64
    const int cg  = blk & 63;
    const int c0  = cg * CH;

    const float4* cwb = cw4 + (size_t)b * NHW;
    const int2*   cpb = cpk + (size_t)b * NHW;
    const float*  fb   = feats + (size_t)(b * NC_ + c0) * NHW;
    float*        dstb = out   + (size_t)(b * NC_ + c0) * NHW;

    #pragma unroll
    for (int k = 0; k < 5; ++k) {
        const int px = k * 320 + threadIdx.x;
        const float4 wv = cwb[px];
        const int2   pk = cpb[px];
        const int o00 = pk.x & 0xffff, o01 = pk.x >> 16;
        const int o10 = pk.y & 0xffff, o11 = pk.y >> 16;
        #pragma unroll
        for (int cc = 0; cc < CH; ++cc) {
            const float* ip = fb + cc * NHW;
            const float r = wv.x * ip[o00] + wv.y * ip[o01]
                          + wv.z * ip[o10] + wv.w * ip[o11];
            __builtin_nontemporal_store(r, &dstb[(size_t)cc * NHW + px]);
        }
    }
}

// ---------------------------------------------------------------------------
// Fallback path (only if ws_size too small): original 3-kernel chain.
// ---------------------------------------------------------------------------
__global__ __launch_bounds__(256) void pool_bn_kernel(
    const float* __restrict__ feats,
    const float* __restrict__ gd, const float* __restrict__ bed,
    const float* __restrict__ rmd, const float* __restrict__ rvd,
    float* __restrict__ pooled)
{
    __shared__ __align__(16) float img[NHW];
    const int bc = blockIdx.x;
    const int b  = bc >> 8;
    const int c  = bc & 255;

    const float4* src4 = (const float4*)(feats + (size_t)bc * NHW);
    for (int i = threadIdx.x; i < NHW / 4; i += 256)
        ((float4*)img)[i] = src4[i];
    __syncthreads();

    if (threadIdx.x < NWIN) {
        const int win = threadIdx.x;
        const int wh  = win >> 3;
        const int ww  = win & 7;
        const int base = (wh * 5) * NW + ww * 5;
        float sum = 0.f;
        #pragma unroll
        for (int i = 0; i < 5; ++i)
            #pragma unroll
            for (int j = 0; j < 5; ++j)
                sum += img[base + i * NW + j];
        float mean = sum * (1.0f / 25.0f);
        float f2m  = (ww < 6) ? (2.0f * mean) : (mean + 1e-5f);
        float inv  = gd[c] / sqrtf(rvd[c] + 1e-5f);
        float v    = f2m * inv + (bed[c] - rmd[c] * inv);
        v = fmaxf(v, 0.0f);
        pooled[((size_t)(b * NWIN + win)) * NC_ + c] = v;
    }
}

__global__ __launch_bounds__(256) void co_M_kernel(
    const float* __restrict__ pooled,
    const float* __restrict__ wd, const float* __restrict__ bd,
    float* __restrict__ Mbuf)
{
    const int blk = blockIdx.x;
    const int tid = threadIdx.x;

    __shared__ float red[4][8];
    __shared__ float co[8];

    const float p = pooled[(size_t)blk * NC_ + tid];
    float part[8];
    #pragma unroll
    for (int o = 0; o < 8; ++o) part[o] = p * wd[o * NC_ + tid];

    const int lane = tid & 63;
    const int wv   = tid >> 6;
    #pragma unroll
    for (int o = 0; o < 8; ++o) {
        float v = part[o];
        #pragma unroll
        for (int off = 32; off > 0; off >>= 1) v += __shfl_down(v, off, 64);
        if (lane == 0) red[wv][o] = v;
    }
    __syncthreads();
    if (tid < 8) co[tid] = red[0][tid] + red[1][tid] + red[2][tid] + red[3][tid] + bd[tid];
    __syncthreads();

    if (tid == 0) {
        const float xr = co[0], yr = co[1], sx = co[2], sy = co[3];
        const float tx0 = co[4], tx1 = co[5], ty0 = co[6], ty1 = co[7];
        const float cx = cosf(xr), sxr = sinf(xr);
        const float cy = cosf(yr), syr = sinf(yr);
        const float s = sx * sy;
        float* m = Mbuf + blk * 6;
        m[0] = (cx * cy - sxr * syr) * s;
        m[1] = (cx * syr + sxr * cy) * s;
        m[2] = sx * (cx * ty0 + sxr * ty1) + tx0;
        m[3] = (-sxr * cy - cx * syr) * s;
        m[4] = (-sxr * syr + cx * cy) * s;
        m[5] = sx * (-sxr * ty0 + cx * ty1) + tx1;
    }
}

__global__ __launch_bounds__(256) void sample_kernel(
    const float* __restrict__ feats,
    const float* __restrict__ Mbuf,
    float* __restrict__ out)
{
    __shared__ __align__(16) float img[NHW];
    __shared__ float Ml[NWIN * 6];

    const int bc = blockIdx.x;
    const int b  = bc >> 8;

    const float4* src4 = (const float4*)(feats + (size_t)bc * NHW);
    for (int i = threadIdx.x; i < NHW / 4; i += 256) {
        float4 v = src4[i];
        const int j = i % (NW / 4);
        if (j < 7)      { v.x *= 2.f; v.y *= 2.f; v.z *= 2.f; v.w *= 2.f; }
        else if (j == 7){ v.x *= 2.f; v.y *= 2.f; v.z += 1e-5f; v.w += 1e-5f; }
        else            { v.x += 1e-5f; v.y += 1e-5f; v.z += 1e-5f; v.w += 1e-5f; }
        ((float4*)img)[i] = v;
    }
    for (int i = threadIdx.x; i < NWIN * 6; i += 256)
        Ml[i] = Mbuf[b * NWIN * 6 + i];
    __syncthreads();

    float* dst = out + (size_t)bc * NHW;
    for (int idx = threadIdx.x; idx < NHW; idx += 256) {
        const int h  = idx / NW;
        const int w  = idx - h * NW;
        const int wh = h / 5, ii = h - wh * 5;
        const int ww = w / 5, jj = w - ww * 5;
        const float* m = &Ml[(wh * 8 + ww) * 6];

        const float wcx = (float)(jj - 2) * (2.0f / 39.0f);
        const float wcy = (float)(ii - 2) * (2.0f / 39.0f);
        const float gx = m[0] * wcx + m[1] * wcy + m[2];
        const float gy = m[3] * wcx + m[4] * wcy + m[5];

        float x = (gx + 1.0f) * 19.5f;
        float y = (gy + 1.0f) * 19.5f;
        x = fminf(fmaxf(x, -1.0e6f), 1.0e6f);
        y = fminf(fmaxf(y, -1.0e6f), 1.0e6f);

        const float x0f = floorf(x), y0f = floorf(y);
        const int x0 = (int)x0f, y0 = (int)y0f;
        const int x1 = x0 + 1,  y1 = y0 + 1;
        const float fx = x - x0f, fy = y - y0f;

        const bool xv0 = (x0 >= 0) & (x0 <= NW - 1);
        const bool xv1 = (x1 >= 0) & (x1 <= NW - 1);
        const bool yv0 = (y0 >= 0) & (y0 <= NH - 1);
        const bool yv1 = (y1 >= 0) & (y1 <= NH - 1);

        const int xc0 = min(max(x0, 0), NW - 1);
        const int xc1 = min(max(x1, 0), NW - 1);
        const int yc0 = min(max(y0, 0), NH - 1);
        const int yc1 = min(max(y1, 0), NH - 1);

        float acc = 0.f;
        acc += img[yc0 * NW + xc0] * ((1.f - fx) * (1.f - fy)) * (float)(xv0 && yv0);
        acc += img[yc0 * NW + xc1] * (fx * (1.f - fy)) * (float)(xv1 && yv0);
        acc += img[yc1 * NW + xc0] * ((1.f - fx) * fy) * (float)(xv0 && yv1);
        acc += img[yc1 * NW + xc1] * (fx * fy) * (float)(xv1 && yv1);

        dst[idx] = acc;
    }
}

// ---------------------------------------------------------------------------
extern "C" void kernel_launch(void* const* d_in, const int* in_sizes, int n_in,
                              void* d_out, int out_size, void* d_ws, size_t ws_size,
                              hipStream_t stream)
{
    (void)in_sizes; (void)n_in; (void)out_size;

    const float* feats = (const float*)d_in[0];
    // d_in[1..8] (w1,b1,g1,be1,rm1,rv1,w2,b2) are dead code in the reference.
    const float* gd  = (const float*)d_in[9];
    const float* bed = (const float*)d_in[10];
    const float* rmd = (const float*)d_in[11];
    const float* rvd = (const float*)d_in[12];
    const float* wd  = (const float*)d_in[13];
    const float* bd  = (const float*)d_in[14];

    float* out = (float*)d_out;

    // d_ws: Mbuf [96 KB, fallback only] | cw4 [1.6 MB] | cpk [0.8 MB]
    const size_t CW_OFF  = 98304;
    const size_t CW_B    = (size_t)NB * NHW * sizeof(float4);   // 1638400
    const size_t CPK_OFF = CW_OFF + CW_B;                       // 1736704
    const size_t CPK_B   = (size_t)NB * NHW * sizeof(int2);     // 819200
    const bool fast = (ws_size >= CPK_OFF + CPK_B);

    if (fast) {
        float4* cw4 = (float4*)((char*)d_ws + CW_OFF);
        int2*   cpk = (int2*)((char*)d_ws + CPK_OFF);
        pool_co_kernel<<<NB * 8, 256, 0, stream>>>(feats, gd, bed, rmd, rvd,
                                                   wd, bd, cw4, cpk);
        sample_gather_kernel<<<NB * (NC_ / CH), 320, 0, stream>>>(feats, cw4, cpk, out);
    } else {
        float* Mbuf   = (float*)d_ws;
        float* pooled = out;   // staged in d_out, overwritten by sample_kernel
        pool_bn_kernel<<<NB * NC_, 256, 0, stream>>>(feats, gd, bed, rmd, rvd, pooled);
        co_M_kernel<<<NB * NWIN, 256, 0, stream>>>(pooled, wd, bd, Mbuf);
        sample_kernel<<<NB * NC_, 256, 0, stream>>>(feats, Mbuf, out);
    }
}

// Round 15
// 58.457 us; speedup vs baseline: 2.0218x; 2.0218x over previous
//
#include <hip/hip_runtime.h>
#include <math.h>

#define NB   64
#define NC_  256
#define NH   40
#define NW   40
#define NHW  1600
#define NWIN 64
#define CH   4          // channels per sample tile
#define PW   44         // padded LDS row stride (floats), 4-aligned
#define IMS  1852       // per-channel slot: 4 guard + 42*44=1848
// channel image: im = img + cc*IMS + 4; pixel (x,y) at im[(y+1)*44 + x].
// Zeroed: guard [0..3], padded rows 0 & 41, cols 40..43 of rows 1..40.
// base = (y0c+1)*44 + x0c, clamped to [-1,39]; corners at +0,+1,+44,+45
// always land in valid or zeroed cells (base=-1 -> guard).
//
// XCD affinity (T1): blockIdx%8 selects the XCD (round-robin dispatch), so
// both kernels map batch b to XCD b%8 — the producer pulls feats[b]+coeffs[b]
// into that XCD's L2 and the 64 sampler blocks of b hit it.

typedef float f32x4 __attribute__((ext_vector_type(4)));

// ---------------------------------------------------------------------------
// FUSED Kernel A+B: pool + BN/ReLU + co + M + folded bilinear coefficients.
// 512 blocks; b = (grp>>3)*8 + (blk&7), wh = grp&7 with grp = blk>>3.
// ---------------------------------------------------------------------------
__global__ __launch_bounds__(256) void pool_co_kernel(
    const float* __restrict__ feats,
    const float* __restrict__ gd, const float* __restrict__ bed,
    const float* __restrict__ rmd, const float* __restrict__ rvd,
    const float* __restrict__ wd, const float* __restrict__ bd,
    float4* __restrict__ cw4, int2* __restrict__ cbc)
{
    __shared__ float pl[8][NC_];      // pooled [ww][c]
    __shared__ __align__(16) float swd[8 * NC_];
    __shared__ float sco[8][8];
    __shared__ float sM6[8][6];

    const int xcd = blockIdx.x & 7;
    const int grp = blockIdx.x >> 3;          // 0..63
    const int b   = (grp >> 3) * 8 + xcd;     // b%8 == xcd
    const int wh  = grp & 7;
    const int t   = threadIdx.x;              // channel

    // stage wd (8x256 floats) into LDS, coalesced
    for (int i = t; i < 512; i += 256)
        ((f32x4*)swd)[i] = ((const f32x4*)wd)[i];

    // 1+2) register pooling for channel t over the wh band
    {
        const f32x4* src = (const f32x4*)(feats + ((size_t)(b * NC_ + t)) * NHW
                                          + wh * 5 * NW);
        float acc[8] = {0.f, 0.f, 0.f, 0.f, 0.f, 0.f, 0.f, 0.f};
        #pragma unroll
        for (int r = 0; r < 5; ++r) {
            #pragma unroll
            for (int j = 0; j < 10; ++j) {
                const f32x4 v = src[r * 10 + j];
                #pragma unroll
                for (int k = 0; k < 4; ++k)
                    acc[(4 * j + k) / 5] += v[k];   // static col-group map
            }
        }
        const float inv  = gd[t] / sqrtf(rvd[t] + 1e-5f);
        const float beta = bed[t] - rmd[t] * inv;
        #pragma unroll
        for (int ww = 0; ww < 8; ++ww) {
            const float mean = acc[ww] * (1.0f / 25.0f);
            const float f2m  = (ww < 6) ? (2.0f * mean) : (mean + 1e-5f);
            pl[ww][t] = fmaxf(f2m * inv + beta, 0.0f);
        }
    }
    __syncthreads();

    // 3) co: two windows per wave (32-lane segments)
    {
        const int w = t >> 5;         // window ww
        const int s = t & 31;
        float po[8] = {0.f, 0.f, 0.f, 0.f, 0.f, 0.f, 0.f, 0.f};
        #pragma unroll
        for (int k = 0; k < 8; ++k) {
            const int c2 = s + 32 * k;
            const float p = pl[w][c2];
            #pragma unroll
            for (int o = 0; o < 8; ++o)
                po[o] += p * swd[o * NC_ + c2];
        }
        #pragma unroll
        for (int o = 0; o < 8; ++o) {
            #pragma unroll
            for (int off = 16; off > 0; off >>= 1)
                po[o] += __shfl_down(po[o], off, 32);
        }
        if (s == 0) {
            #pragma unroll
            for (int o = 0; o < 8; ++o) sco[w][o] = po[o] + bd[o];
        }
    }
    __syncthreads();

    // 4) affine M per window
    if (t < 8) {
        const float xr = sco[t][0], yr = sco[t][1], sx = sco[t][2], sy = sco[t][3];
        const float tx0 = sco[t][4], tx1 = sco[t][5], ty0 = sco[t][6], ty1 = sco[t][7];
        const float cx = cosf(xr), sxr = sinf(xr);
        const float cy = cosf(yr), syr = sinf(yr);
        const float s = sx * sy;
        sM6[t][0] = (cx * cy - sxr * syr) * s;           // M00
        sM6[t][1] = (cx * syr + sxr * cy) * s;           // M01
        sM6[t][2] = sx * (cx * ty0 + sxr * ty1) + tx0;   // M02
        sM6[t][3] = (-sxr * cy - cx * syr) * s;          // M10
        sM6[t][4] = (-sxr * syr + cx * cy) * s;          // M11
        sM6[t][5] = sx * (-sxr * ty0 + cx * ty1) + tx1;  // M12
    }
    __syncthreads();

    // 5) folded bilinear coefficients: 8 windows x 25 px
    if (t < 200) {
        const int w   = t / 25;       // ww
        const int pxi = t - w * 25;
        const int ii  = pxi / 5;
        const int jj  = pxi - ii * 5;
        const float* m = sM6[w];

        const float wcx = (float)(jj - 2) * (2.0f / 39.0f);
        const float wcy = (float)(ii - 2) * (2.0f / 39.0f);
        const float gx = m[0] * wcx + m[1] * wcy + m[2];
        const float gy = m[3] * wcx + m[4] * wcy + m[5];

        float x = (gx + 1.0f) * 19.5f;
        float y = (gy + 1.0f) * 19.5f;
        x = fminf(fmaxf(x, -1.0e6f), 1.0e6f);
        y = fminf(fmaxf(y, -1.0e6f), 1.0e6f);

        const float x0f = floorf(x), y0f = floorf(y);
        const int x0 = (int)x0f, y0 = (int)y0f;
        const int x1 = x0 + 1,  y1 = y0 + 1;
        const float fx = x - x0f, fy = y - y0f;

        const bool xv0 = (x0 >= 0) & (x0 <= NW - 1);
        const bool xv1 = (x1 >= 0) & (x1 <= NW - 1);
        const bool yv0 = (y0 >= 0) & (y0 <= NH - 1);
        const bool yv1 = (y1 >= 0) & (y1 <= NH - 1);

        const float w00 = (1.f - fx) * (1.f - fy) * (float)(xv0 && yv0);
        const float w01 = fx * (1.f - fy) * (float)(xv1 && yv0);
        const float w10 = (1.f - fx) * fy * (float)(xv0 && yv1);
        const float w11 = fx * fy * (float)(xv1 && yv1);

        const int xc0 = min(max(x0, 0), NW - 1);
        const int xc1 = min(max(x1, 0), NW - 1);
        const float a0 = (xc0 < 30) ? 2.f : 1.f;
        const float a1 = (xc1 < 30) ? 2.f : 1.f;
        const float d0 = (xc0 < 30) ? 0.f : 1e-5f;
        const float d1 = (xc1 < 30) ? 0.f : 1e-5f;

        float4 wvec;
        wvec.x = w00 * a0;
        wvec.y = w01 * a1;
        wvec.z = w10 * a0;
        wvec.w = w11 * a1;
        const float cst = (w00 + w10) * d0 + (w01 + w11) * d1;

        const int xb = min(max(x0, -1), NW - 1);
        const int yb = min(max(y0, -1), NH - 1);
        const int base = (yb + 1) * PW + xb;

        const int h    = wh * 5 + ii;
        const int wcol = w * 5 + jj;
        const int pidx = b * NHW + h * NW + wcol;
        cw4[pidx] = wvec;
        cbc[pidx] = make_int2(base, __float_as_int(cst));
    }
}

// ---------------------------------------------------------------------------
// Kernel C: lean LDS sampler (r13-proven) with XCD-affine b mapping.
// 4096 blocks; b = (j>>6)*8 + (blk&7), cg = j&63 with j = blk>>3.
// ---------------------------------------------------------------------------
__global__ __launch_bounds__(320) void sample_lean_kernel(
    const float* __restrict__ feats,
    const float4* __restrict__ cw4, const int2* __restrict__ cbc,
    float* __restrict__ out)
{
    __shared__ __align__(16) float img[CH * IMS];

    const int xcd = blockIdx.x & 7;
    const int j   = blockIdx.x >> 3;          // 0..511
    const int b   = (j >> 6) * 8 + xcd;       // b%8 == xcd
    const int cg  = j & 63;
    const int c0  = cg * CH;

    // prefetch coefficients (consumed after the staging barrier)
    const float4* cwb = cw4 + (size_t)b * NHW;
    const int2*   cbb = cbc + (size_t)b * NHW;
    float4 wv[5];
    int2   pc[5];
    #pragma unroll
    for (int k = 0; k < 5; ++k) {
        wv[k] = cwb[k * 320 + threadIdx.x];
        pc[k] = cbb[k * 320 + threadIdx.x];
    }

    // zero guards + borders: 63 float4 per channel.
    for (int i = threadIdx.x; i < CH * 63; i += 320) {
        const int cc = i / 63;
        const int t  = i - cc * 63;
        float* im = img + cc * IMS + 4;
        f32x4 z = {0.f, 0.f, 0.f, 0.f};
        if (t == 0)       *(f32x4*)(img + cc * IMS) = z;              // guard
        else if (t <= 11) *(f32x4*)(im + (t - 1) * 4) = z;            // row 0
        else if (t <= 22) *(f32x4*)(im + 41 * PW + (t - 12) * 4) = z; // row 41
        else              *(f32x4*)(im + (t - 22) * PW + 40) = z;     // cols 40..43
    }

    // stage CH raw images: group g (80 threads) owns channel g.
    {
        const int g   = threadIdx.x / 80;
        const int r80 = threadIdx.x - g * 80;
        const int rb  = r80 / 10;
        const int cb  = r80 - rb * 10;
        const float* src = feats + (size_t)(b * NC_ + c0 + g) * NHW;
        float* dst = img + g * IMS + 4 + PW;
        #pragma unroll
        for (int m = 0; m < 5; ++m) {
            const f32x4 v = *((const f32x4*)src + (m * 80 + r80));
            *(f32x4*)(dst + (m * 8 + rb) * PW + cb * 4) = v;
        }
    }
    __syncthreads();

    float* dstb = out + (size_t)(b * NC_ + c0) * NHW;

    #pragma unroll
    for (int k = 0; k < 5; ++k) {
        const int px = k * 320 + threadIdx.x;
        const int   base = pc[k].x;
        const float cst  = __int_as_float(pc[k].y);
        #pragma unroll
        for (int cc = 0; cc < CH; ++cc) {
            const float* ip = img + cc * IMS + 4 + base;
            const float r = cst + wv[k].x * ip[0]  + wv[k].y * ip[1]
                                + wv[k].z * ip[PW] + wv[k].w * ip[PW + 1];
            __builtin_nontemporal_store(r, &dstb[(size_t)cc * NHW + px]);
        }
    }
}

// ---------------------------------------------------------------------------
// Fallback path (only if ws_size too small): original 3-kernel chain.
// ---------------------------------------------------------------------------
__global__ __launch_bounds__(256) void pool_bn_kernel(
    const float* __restrict__ feats,
    const float* __restrict__ gd, const float* __restrict__ bed,
    const float* __restrict__ rmd, const float* __restrict__ rvd,
    float* __restrict__ pooled)
{
    __shared__ __align__(16) float img[NHW];
    const int bc = blockIdx.x;
    const int b  = bc >> 8;
    const int c  = bc & 255;

    const float4* src4 = (const float4*)(feats + (size_t)bc * NHW);
    for (int i = threadIdx.x; i < NHW / 4; i += 256)
        ((float4*)img)[i] = src4[i];
    __syncthreads();

    if (threadIdx.x < NWIN) {
        const int win = threadIdx.x;
        const int wh  = win >> 3;
        const int ww  = win & 7;
        const int base = (wh * 5) * NW + ww * 5;
        float sum = 0.f;
        #pragma unroll
        for (int i = 0; i < 5; ++i)
            #pragma unroll
            for (int j = 0; j < 5; ++j)
                sum += img[base + i * NW + j];
        float mean = sum * (1.0f / 25.0f);
        float f2m  = (ww < 6) ? (2.0f * mean) : (mean + 1e-5f);
        float inv  = gd[c] / sqrtf(rvd[c] + 1e-5f);
        float v    = f2m * inv + (bed[c] - rmd[c] * inv);
        v = fmaxf(v, 0.0f);
        pooled[((size_t)(b * NWIN + win)) * NC_ + c] = v;
    }
}

__global__ __launch_bounds__(256) void co_M_kernel(
    const float* __restrict__ pooled,
    const float* __restrict__ wd, const float* __restrict__ bd,
    float* __restrict__ Mbuf)
{
    const int blk = blockIdx.x;
    const int tid = threadIdx.x;

    __shared__ float red[4][8];
    __shared__ float co[8];

    const float p = pooled[(size_t)blk * NC_ + tid];
    float part[8];
    #pragma unroll
    for (int o = 0; o < 8; ++o) part[o] = p * wd[o * NC_ + tid];

    const int lane = tid & 63;
    const int wv   = tid >> 6;
    #pragma unroll
    for (int o = 0; o < 8; ++o) {
        float v = part[o];
        #pragma unroll
        for (int off = 32; off > 0; off >>= 1) v += __shfl_down(v, off, 64);
        if (lane == 0) red[wv][o] = v;
    }
    __syncthreads();
    if (tid < 8) co[tid] = red[0][tid] + red[1][tid] + red[2][tid] + red[3][tid] + bd[tid];
    __syncthreads();

    if (tid == 0) {
        const float xr = co[0], yr = co[1], sx = co[2], sy = co[3];
        const float tx0 = co[4], tx1 = co[5], ty0 = co[6], ty1 = co[7];
        const float cx = cosf(xr), sxr = sinf(xr);
        const float cy = cosf(yr), syr = sinf(yr);
        const float s = sx * sy;
        float* m = Mbuf + blk * 6;
        m[0] = (cx * cy - sxr * syr) * s;
        m[1] = (cx * syr + sxr * cy) * s;
        m[2] = sx * (cx * ty0 + sxr * ty1) + tx0;
        m[3] = (-sxr * cy - cx * syr) * s;
        m[4] = (-sxr * syr + cx * cy) * s;
        m[5] = sx * (-sxr * ty0 + cx * ty1) + tx1;
    }
}

__global__ __launch_bounds__(256) void sample_kernel(
    const float* __restrict__ feats,
    const float* __restrict__ Mbuf,
    float* __restrict__ out)
{
    __shared__ __align__(16) float img[NHW];
    __shared__ float Ml[NWIN * 6];

    const int bc = blockIdx.x;
    const int b  = bc >> 8;

    const float4* src4 = (const float4*)(feats + (size_t)bc * NHW);
    for (int i = threadIdx.x; i < NHW / 4; i += 256) {
        float4 v = src4[i];
        const int j = i % (NW / 4);
        if (j < 7)      { v.x *= 2.f; v.y *= 2.f; v.z *= 2.f; v.w *= 2.f; }
        else if (j == 7){ v.x *= 2.f; v.y *= 2.f; v.z += 1e-5f; v.w += 1e-5f; }
        else            { v.x += 1e-5f; v.y += 1e-5f; v.z += 1e-5f; v.w += 1e-5f; }
        ((float4*)img)[i] = v;
    }
    for (int i = threadIdx.x; i < NWIN * 6; i += 256)
        Ml[i] = Mbuf[b * NWIN * 6 + i];
    __syncthreads();

    float* dst = out + (size_t)bc * NHW;
    for (int idx = threadIdx.x; idx < NHW; idx += 256) {
        const int h  = idx / NW;
        const int w  = idx - h * NW;
        const int wh = h / 5, ii = h - wh * 5;
        const int ww = w / 5, jj = w - ww * 5;
        const float* m = &Ml[(wh * 8 + ww) * 6];

        const float wcx = (float)(jj - 2) * (2.0f / 39.0f);
        const float wcy = (float)(ii - 2) * (2.0f / 39.0f);
        const float gx = m[0] * wcx + m[1] * wcy + m[2];
        const float gy = m[3] * wcx + m[4] * wcy + m[5];

        float x = (gx + 1.0f) * 19.5f;
        float y = (gy + 1.0f) * 19.5f;
        x = fminf(fmaxf(x, -1.0e6f), 1.0e6f);
        y = fminf(fmaxf(y, -1.0e6f), 1.0e6f);

        const float x0f = floorf(x), y0f = floorf(y);
        const int x0 = (int)x0f, y0 = (int)y0f;
        const int x1 = x0 + 1,  y1 = y0 + 1;
        const float fx = x - x0f, fy = y - y0f;

        const bool xv0 = (x0 >= 0) & (x0 <= NW - 1);
        const bool xv1 = (x1 >= 0) & (x1 <= NW - 1);
        const bool yv0 = (y0 >= 0) & (y0 <= NH - 1);
        const bool yv1 = (y1 >= 0) & (y1 <= NH - 1);

        const int xc0 = min(max(x0, 0), NW - 1);
        const int xc1 = min(max(x1, 0), NW - 1);
        const int yc0 = min(max(y0, 0), NH - 1);
        const int yc1 = min(max(y1, 0), NH - 1);

        float acc = 0.f;
        acc += img[yc0 * NW + xc0] * ((1.f - fx) * (1.f - fy)) * (float)(xv0 && yv0);
        acc += img[yc0 * NW + xc1] * (fx * (1.f - fy)) * (float)(xv1 && yv0);
        acc += img[yc1 * NW + xc0] * ((1.f - fx) * fy) * (float)(xv0 && yv1);
        acc += img[yc1 * NW + xc1] * (fx * fy) * (float)(xv1 && yv1);

        dst[idx] = acc;
    }
}

// ---------------------------------------------------------------------------
extern "C" void kernel_launch(void* const* d_in, const int* in_sizes, int n_in,
                              void* d_out, int out_size, void* d_ws, size_t ws_size,
                              hipStream_t stream)
{
    (void)in_sizes; (void)n_in; (void)out_size;

    const float* feats = (const float*)d_in[0];
    // d_in[1..8] (w1,b1,g1,be1,rm1,rv1,w2,b2) are dead code in the reference.
    const float* gd  = (const float*)d_in[9];
    const float* bed = (const float*)d_in[10];
    const float* rmd = (const float*)d_in[11];
    const float* rvd = (const float*)d_in[12];
    const float* wd  = (const float*)d_in[13];
    const float* bd  = (const float*)d_in[14];

    float* out = (float*)d_out;

    // d_ws: Mbuf [96 KB, fallback only] | cw4 [1.6 MB] | cbc [0.8 MB]
    const size_t CW_OFF  = 98304;
    const size_t CW_B    = (size_t)NB * NHW * sizeof(float4);   // 1638400
    const size_t CBC_OFF = CW_OFF + CW_B;                       // 1736704
    const size_t CBC_B   = (size_t)NB * NHW * sizeof(int2);     // 819200
    const bool fast = (ws_size >= CBC_OFF + CBC_B);

    if (fast) {
        float4* cw4 = (float4*)((char*)d_ws + CW_OFF);
        int2*   cbc = (int2*)((char*)d_ws + CBC_OFF);
        pool_co_kernel<<<NB * 8, 256, 0, stream>>>(feats, gd, bed, rmd, rvd,
                                                   wd, bd, cw4, cbc);
        sample_lean_kernel<<<NB * (NC_ / CH), 320, 0, stream>>>(feats, cw4, cbc, out);
    } else {
        float* Mbuf   = (float*)d_ws;
        float* pooled = out;   // staged in d_out, overwritten by sample_kernel
        pool_bn_kernel<<<NB * NC_, 256, 0, stream>>>(feats, gd, bed, rmd, rvd, pooled);
        co_M_kernel<<<NB * NWIN, 256, 0, stream>>>(pooled, wd, bd, Mbuf);
        sample_kernel<<<NB * NC_, 256, 0, stream>>>(feats, Mbuf, out);
    }
}